// Round 6
// baseline (1149.663 us; speedup 1.0000x reference)
//
#include <hip/hip_runtime.h>

#define D 128
#define BN_EPS 1e-5f
#define SB 256   // scan blocks
#define ST 256   // scan threads

typedef short s16x8 __attribute__((ext_vector_type(8)));
typedef float f32x4 __attribute__((ext_vector_type(4)));

// fp32 -> bf16 with round-to-nearest-even
static __device__ __forceinline__ short f2bf(float f) {
    unsigned u = __builtin_bit_cast(unsigned, f);
    u += 0x7FFFu + ((u >> 16) & 1u);
    return (short)(u >> 16);
}

// ---------------- 1. histogram: deg[dst]++ --------------------------------
__global__ __launch_bounds__(256) void k_hist(
    const int* __restrict__ ei, int* __restrict__ deg, int E)
{
    int e = blockIdx.x * 256 + threadIdx.x;
    if (e >= E) return;
    atomicAdd(&deg[ei[E + e]], 1);
}

// ---------------- 2a. per-block partial sums -------------------------------
__global__ __launch_bounds__(ST) void k_scanA(
    const int* __restrict__ deg, int* __restrict__ bsum, int N, int chunk)
{
    int b = blockIdx.x;
    int start = b * chunk, end = min(start + chunk, N);
    int s = 0;
    for (int i = start + threadIdx.x; i < end; i += ST) s += deg[i];
    __shared__ int red[ST];
    red[threadIdx.x] = s;
    __syncthreads();
    for (int o = ST / 2; o > 0; o >>= 1) {
        if (threadIdx.x < o) red[threadIdx.x] += red[threadIdx.x + o];
        __syncthreads();
    }
    if (threadIdx.x == 0) bsum[b] = red[0];
}

// ---------------- 2b. exclusive scan of block sums (1 block) ---------------
__global__ __launch_bounds__(SB) void k_scanB(int* __restrict__ bsum)
{
    __shared__ int tmp[SB];
    int t = threadIdx.x;
    int orig = bsum[t];
    tmp[t] = orig;
    __syncthreads();
    for (int o = 1; o < SB; o <<= 1) {
        int u = (t >= o) ? tmp[t - o] : 0;
        __syncthreads();
        tmp[t] += u;
        __syncthreads();
    }
    bsum[t] = tmp[t] - orig;   // exclusive
}

// ---------------- 2c. per-block scan with base → offsets + cursor ----------
__global__ __launch_bounds__(ST) void k_scanC(
    const int* __restrict__ deg, const int* __restrict__ bsum,
    int* __restrict__ offs, int* __restrict__ cur, int N, int chunk)
{
    int b = blockIdx.x;
    int start = b * chunk, end = min(start + chunk, N);
    __shared__ int tmp[ST];
    __shared__ int carry;
    int t = threadIdx.x;
    if (t == 0) carry = bsum[b];
    __syncthreads();
    for (int i0 = start; i0 < end; i0 += ST) {
        int i = i0 + t;
        int v = (i < end) ? deg[i] : 0;
        tmp[t] = v;
        __syncthreads();
        for (int o = 1; o < ST; o <<= 1) {
            int u = (t >= o) ? tmp[t - o] : 0;
            __syncthreads();
            tmp[t] += u;
            __syncthreads();
        }
        int incl = tmp[t];
        int total = tmp[ST - 1];
        if (i < end) {
            int ex = carry + incl - v;
            offs[i] = ex;
            cur[i] = ex;
        }
        __syncthreads();
        if (t == 0) carry += total;
        __syncthreads();
    }
}

// ---------------- 3. scatter (src, eid) into dst buckets -------------------
__global__ __launch_bounds__(256) void k_scatter(
    const int* __restrict__ ei, int* __restrict__ cur,
    int2* __restrict__ bucket, int E)
{
    int e = blockIdx.x * 256 + threadIdx.x;
    if (e >= E) return;
    int dst = ei[E + e];
    int pos = atomicAdd(&cur[dst], 1);
    bucket[pos] = make_int2(ei[e], e);
}

// ---------------- 4. aggregate: h[n] = x[n] + sum relu(x[src]+ea[eid]) -----
// one 64-lane wave per node, float2 per lane; unroll x4 (proven round 5)
__global__ __launch_bounds__(256) void k_aggr(
    const float* __restrict__ x, const float* __restrict__ ea,
    const int2* __restrict__ bucket, const int* __restrict__ offs,
    const int* __restrict__ deg, float* __restrict__ h, int N)
{
    int node = blockIdx.x * 4 + (threadIdx.x >> 6);
    if (node >= N) return;
    int lane = threadIdx.x & 63;
    int c0 = 2 * lane;
    int start = offs[node];
    int d = deg[node];
    const int2* bp = bucket + start;

    float2 acc = *(const float2*)(x + (size_t)node * D + c0);  // (1+eps)*x_i, eps=0

    int e = 0;
    for (; e + 4 <= d; e += 4) {
        int2 b0 = bp[e];
        int2 b1 = bp[e + 1];
        int2 b2 = bp[e + 2];
        int2 b3 = bp[e + 3];
        float2 x0 = *(const float2*)(x + (size_t)b0.x * D + c0);
        float2 a0 = *(const float2*)(ea + (size_t)b0.y * D + c0);
        float2 x1 = *(const float2*)(x + (size_t)b1.x * D + c0);
        float2 a1 = *(const float2*)(ea + (size_t)b1.y * D + c0);
        float2 x2 = *(const float2*)(x + (size_t)b2.x * D + c0);
        float2 a2 = *(const float2*)(ea + (size_t)b2.y * D + c0);
        float2 x3 = *(const float2*)(x + (size_t)b3.x * D + c0);
        float2 a3 = *(const float2*)(ea + (size_t)b3.y * D + c0);
        acc.x += fmaxf(x0.x + a0.x, 0.f) + fmaxf(x1.x + a1.x, 0.f)
               + fmaxf(x2.x + a2.x, 0.f) + fmaxf(x3.x + a3.x, 0.f);
        acc.y += fmaxf(x0.y + a0.y, 0.f) + fmaxf(x1.y + a1.y, 0.f)
               + fmaxf(x2.y + a2.y, 0.f) + fmaxf(x3.y + a3.y, 0.f);
    }
    for (; e < d; ++e) {
        int2 b = bp[e];
        float2 xv = *(const float2*)(x + (size_t)b.x * D + c0);
        float2 av = *(const float2*)(ea + (size_t)b.y * D + c0);
        acc.x += fmaxf(xv.x + av.x, 0.f);
        acc.y += fmaxf(xv.y + av.y, 0.f);
    }
    *(float2*)(h + (size_t)node * D + c0) = acc;
}

// ---------------- MFMA GEMM: out = [relu](hin @ W + bias), optional BN stats
// 4 waves/block; each wave: one 16-row tile x 128 cols = 8 col-tiles x 4
// k-steps of v_mfma_f32_16x16x32_bf16. W staged once/block into frag-packed
// bf16 LDS (conflict-free b128 reads). In-place safe (wave reads its own 16
// rows before writing them; no restrict on aliased ptrs).
// Layouts (m89-verified C/D; matching A/B):
//   A[i][k]:  lane = i + 16*(k/8),  elem = k%8
//   B[k][j]:  lane = j + 16*(k/8),  elem = k%8
//   D[i][j]:  lane = j + 16*(i/4),  reg  = i%4
template<int RELU_STATS>
__global__ __launch_bounds__(256) void k_mgemm(
    const float* hin, const float* Wg, const float* bias,
    float* outp, float* gsum, float* gsq, int N)
{
    __shared__ __align__(16) short wB[D * D];   // 32KB bf16, frag-packed
    int tid = threadIdx.x;
    // stage W: element (k, n0..n0+3) -> frag slot
    for (int q = tid; q < D * D / 4; q += 256) {
        int k  = q >> 5;
        int n0 = (q & 31) * 4;
        float4 w = *(const float4*)&Wg[k * D + n0];
        int t = k >> 5, g = (k >> 3) & 3, m = k & 7;
        int c = n0 >> 4;
        int lb = g * 16 + (n0 & 15);
        int base = ((t * 8 + c) * 64) * 8 + m;
        wB[base + (lb + 0) * 8] = f2bf(w.x);
        wB[base + (lb + 1) * 8] = f2bf(w.y);
        wB[base + (lb + 2) * 8] = f2bf(w.z);
        wB[base + (lb + 3) * 8] = f2bf(w.w);
    }
    __syncthreads();

    int wv = tid >> 6, l = tid & 63;
    int cl = l & 15, kg = l >> 4;

    float bv[8];
    #pragma unroll
    for (int c = 0; c < 8; ++c) bv[c] = bias[c * 16 + cl];

    float sc[8], sq[8];
    #pragma unroll
    for (int c = 0; c < 8; ++c) { sc[c] = 0.f; sq[c] = 0.f; }

    for (int tile = blockIdx.x * 4 + wv; tile * 16 < N; tile += gridDim.x * 4) {
        int row0 = tile * 16;
        int arow = min(row0 + cl, N - 1);
        const float* ap = hin + (size_t)arow * D + kg * 8;
        s16x8 aF[4];
        #pragma unroll
        for (int t = 0; t < 4; ++t) {
            float4 lo = *(const float4*)(ap + 32 * t);
            float4 hi = *(const float4*)(ap + 32 * t + 4);
            s16x8 a;
            a[0] = f2bf(lo.x); a[1] = f2bf(lo.y); a[2] = f2bf(lo.z); a[3] = f2bf(lo.w);
            a[4] = f2bf(hi.x); a[5] = f2bf(hi.y); a[6] = f2bf(hi.z); a[7] = f2bf(hi.w);
            aF[t] = a;
        }
        #pragma unroll
        for (int c = 0; c < 8; ++c) {
            f32x4 acc = { bv[c], bv[c], bv[c], bv[c] };
            #pragma unroll
            for (int t = 0; t < 4; ++t) {
                s16x8 bF = *(const s16x8*)&wB[((t * 8 + c) * 64 + l) * 8];
                acc = __builtin_amdgcn_mfma_f32_16x16x32_bf16(aF[t], bF, acc, 0, 0, 0);
            }
            int col = c * 16 + cl;
            #pragma unroll
            for (int r = 0; r < 4; ++r) {
                int row = row0 + kg * 4 + r;
                if (row < N) {
                    float o = acc[r];
                    if (RELU_STATS) o = fmaxf(o, 0.f);
                    outp[(size_t)row * D + col] = o;
                    if (RELU_STATS) { sc[c] += o; sq[c] += o * o; }
                }
            }
        }
    }
    if (RELU_STATS) {
        #pragma unroll
        for (int c = 0; c < 8; ++c) {
            atomicAdd(&gsum[c * 16 + cl], sc[c]);
            atomicAdd(&gsq[c * 16 + cl], sq[c]);
        }
    }
}

// ---------------- fold BN into W2/b2 ---------------------------------------
__global__ __launch_bounds__(128) void k_fold(
    const float* __restrict__ gsum, const float* __restrict__ gsq,
    const float* __restrict__ gamma, const float* __restrict__ beta,
    const float* __restrict__ W2, const float* __restrict__ b2,
    float* __restrict__ W2p, float* __restrict__ b2p, int N)
{
    __shared__ float sS[D], tS[D];
    int j = threadIdx.x;
    float invN = 1.0f / (float)N;
    float mean = gsum[j] * invN;
    float var = gsq[j] * invN - mean * mean;
    float rstd = rsqrtf(var + BN_EPS);
    float s = rstd * gamma[j];
    sS[j] = s;
    tS[j] = beta[j] - mean * s;
    __syncthreads();
    float acc = b2[j];
    #pragma unroll 4
    for (int k = 0; k < D; ++k) {
        float w = W2[k * D + j];
        W2p[k * D + j] = sS[k] * w;
        acc = fmaf(tS[k], w, acc);
    }
    b2p[j] = acc;
}

extern "C" void kernel_launch(void* const* d_in, const int* in_sizes, int n_in,
                              void* d_out, int out_size, void* d_ws, size_t ws_size,
                              hipStream_t stream) {
    const float* x     = (const float*)d_in[0];
    const int*   ei    = (const int*)d_in[1];
    const float* ea    = (const float*)d_in[2];
    const float* W1    = (const float*)d_in[3];
    const float* b1    = (const float*)d_in[4];
    const float* gamma = (const float*)d_in[5];
    const float* beta  = (const float*)d_in[6];
    const float* W2    = (const float*)d_in[7];
    const float* b2    = (const float*)d_in[8];
    float* out = (float*)d_out;

    int N = in_sizes[0] / D;
    int E = in_sizes[1] / 2;

    // ---- workspace layout (~14.1 MB, proven safe) ----
    char* ws = (char*)d_ws;
    int2*  bucket = (int2*)ws;                             // E int2 (12.8 MB)
    int*   deg    = (int*)(ws + (size_t)E * sizeof(int2)); // N
    int*   offs   = deg + N;                               // N
    int*   cur    = offs + N;                              // N
    int*   bsum   = cur + N;                               // SB
    float* gsum   = (float*)(bsum + SB);                   // D
    float* gsq    = gsum + D;                              // D
    float* W2p    = gsq + D;                               // D*D
    float* b2p    = W2p + D * D;                           // D

    // zero deg + bsum + gsum + gsq (bucket/offs/cur fully overwritten)
    hipMemsetAsync(deg, 0, ((size_t)3 * N + SB) * sizeof(int) + 2 * D * sizeof(float), stream);

    int chunk = (N + SB - 1) / SB;
    int eB = (E + 255) / 256;

    k_hist<<<eB, 256, 0, stream>>>(ei, deg, E);
    k_scanA<<<SB, ST, 0, stream>>>(deg, bsum, N, chunk);
    k_scanB<<<1, SB, 0, stream>>>(bsum);
    k_scanC<<<SB, ST, 0, stream>>>(deg, bsum, offs, cur, N, chunk);
    k_scatter<<<eB, 256, 0, stream>>>(ei, cur, bucket, E);
    k_aggr<<<(N + 3) / 4, 256, 0, stream>>>(x, ea, bucket, offs, deg, out, N);

    k_mgemm<1><<<512, 256, 0, stream>>>(out, W1, b1, out, gsum, gsq, N);
    k_fold<<<1, 128, 0, stream>>>(gsum, gsq, gamma, beta, W2, b2, W2p, b2p, N);
    k_mgemm<0><<<512, 256, 0, stream>>>(out, W2p, b2p, out, gsum, gsq, N);
}

// Round 7
// 535.179 us; speedup vs baseline: 2.1482x; 2.1482x over previous
//
#include <hip/hip_runtime.h>

#define D 128
#define BN_EPS 1e-5f
#define SB 256   // scan blocks
#define ST 256   // scan threads

typedef short s16x8 __attribute__((ext_vector_type(8)));
typedef float f32x4 __attribute__((ext_vector_type(4)));

// fp32 -> bf16 round-to-nearest-even
static __device__ __forceinline__ short f2bf(float f) {
    unsigned u = __builtin_bit_cast(unsigned, f);
    u += 0x7FFFu + ((u >> 16) & 1u);
    return (short)(u >> 16);
}

// packed-fragment slot for W element (k, f):
//   t=k>>5, kg=(k>>3)&3, e=k&7, c=f>>4, fl=f&15, lane=kg*16+fl
//   idx = ((t*8+c)*64 + lane)*8 + e     (shorts)
static __device__ __forceinline__ int wslot(int k, int f) {
    int t = k >> 5, kg = (k >> 3) & 3, e = k & 7;
    int c = f >> 4, fl = f & 15;
    return (((t * 8 + c) * 64 + kg * 16 + fl) * 8) + e;
}

// ---------------- 1. histogram: deg[dst]++ --------------------------------
__global__ __launch_bounds__(256) void k_hist(
    const int* __restrict__ ei, int* __restrict__ deg, int E)
{
    int e = blockIdx.x * 256 + threadIdx.x;
    if (e >= E) return;
    atomicAdd(&deg[ei[E + e]], 1);
}

// ---------------- 2a. per-block partial sums -------------------------------
__global__ __launch_bounds__(ST) void k_scanA(
    const int* __restrict__ deg, int* __restrict__ bsum, int N, int chunk)
{
    int b = blockIdx.x;
    int start = b * chunk, end = min(start + chunk, N);
    int s = 0;
    for (int i = start + threadIdx.x; i < end; i += ST) s += deg[i];
    __shared__ int red[ST];
    red[threadIdx.x] = s;
    __syncthreads();
    for (int o = ST / 2; o > 0; o >>= 1) {
        if (threadIdx.x < o) red[threadIdx.x] += red[threadIdx.x + o];
        __syncthreads();
    }
    if (threadIdx.x == 0) bsum[b] = red[0];
}

// ---------------- 2b. exclusive scan of block sums (1 block) ---------------
__global__ __launch_bounds__(SB) void k_scanB(int* __restrict__ bsum)
{
    __shared__ int tmp[SB];
    int t = threadIdx.x;
    int orig = bsum[t];
    tmp[t] = orig;
    __syncthreads();
    for (int o = 1; o < SB; o <<= 1) {
        int u = (t >= o) ? tmp[t - o] : 0;
        __syncthreads();
        tmp[t] += u;
        __syncthreads();
    }
    bsum[t] = tmp[t] - orig;   // exclusive
}

// ---------------- 2c. per-block scan with base → offsets + cursor ----------
__global__ __launch_bounds__(ST) void k_scanC(
    const int* __restrict__ deg, const int* __restrict__ bsum,
    int* __restrict__ offs, int* __restrict__ cur, int N, int chunk)
{
    int b = blockIdx.x;
    int start = b * chunk, end = min(start + chunk, N);
    __shared__ int tmp[ST];
    __shared__ int carry;
    int t = threadIdx.x;
    if (t == 0) carry = bsum[b];
    __syncthreads();
    for (int i0 = start; i0 < end; i0 += ST) {
        int i = i0 + t;
        int v = (i < end) ? deg[i] : 0;
        tmp[t] = v;
        __syncthreads();
        for (int o = 1; o < ST; o <<= 1) {
            int u = (t >= o) ? tmp[t - o] : 0;
            __syncthreads();
            tmp[t] += u;
            __syncthreads();
        }
        int incl = tmp[t];
        int total = tmp[ST - 1];
        if (i < end) {
            int ex = carry + incl - v;
            offs[i] = ex;
            cur[i] = ex;
        }
        __syncthreads();
        if (t == 0) carry += total;
        __syncthreads();
    }
}

// ---------------- 3. scatter (src, eid) into dst buckets -------------------
__global__ __launch_bounds__(256) void k_scatter(
    const int* __restrict__ ei, int* __restrict__ cur,
    int2* __restrict__ bucket, int E)
{
    int e = blockIdx.x * 256 + threadIdx.x;
    if (e >= E) return;
    int dst = ei[E + e];
    int pos = atomicAdd(&cur[dst], 1);
    bucket[pos] = make_int2(ei[e], e);
}

// ---------------- 4. aggregate: h[n] = x[n] + sum relu(x[src]+ea[eid]) -----
// one 64-lane wave per node, float2 per lane; unroll x4 (proven round 5)
__global__ __launch_bounds__(256) void k_aggr(
    const float* __restrict__ x, const float* __restrict__ ea,
    const int2* __restrict__ bucket, const int* __restrict__ offs,
    const int* __restrict__ deg, float* __restrict__ h, int N)
{
    int node = blockIdx.x * 4 + (threadIdx.x >> 6);
    if (node >= N) return;
    int lane = threadIdx.x & 63;
    int c0 = 2 * lane;
    int start = offs[node];
    int d = deg[node];
    const int2* bp = bucket + start;

    float2 acc = *(const float2*)(x + (size_t)node * D + c0);

    int e = 0;
    for (; e + 4 <= d; e += 4) {
        int2 b0 = bp[e];
        int2 b1 = bp[e + 1];
        int2 b2 = bp[e + 2];
        int2 b3 = bp[e + 3];
        float2 x0 = *(const float2*)(x + (size_t)b0.x * D + c0);
        float2 a0 = *(const float2*)(ea + (size_t)b0.y * D + c0);
        float2 x1 = *(const float2*)(x + (size_t)b1.x * D + c0);
        float2 a1 = *(const float2*)(ea + (size_t)b1.y * D + c0);
        float2 x2 = *(const float2*)(x + (size_t)b2.x * D + c0);
        float2 a2 = *(const float2*)(ea + (size_t)b2.y * D + c0);
        float2 x3 = *(const float2*)(x + (size_t)b3.x * D + c0);
        float2 a3 = *(const float2*)(ea + (size_t)b3.y * D + c0);
        acc.x += fmaxf(x0.x + a0.x, 0.f) + fmaxf(x1.x + a1.x, 0.f)
               + fmaxf(x2.x + a2.x, 0.f) + fmaxf(x3.x + a3.x, 0.f);
        acc.y += fmaxf(x0.y + a0.y, 0.f) + fmaxf(x1.y + a1.y, 0.f)
               + fmaxf(x2.y + a2.y, 0.f) + fmaxf(x3.y + a3.y, 0.f);
    }
    for (; e < d; ++e) {
        int2 b = bp[e];
        float2 xv = *(const float2*)(x + (size_t)b.x * D + c0);
        float2 av = *(const float2*)(ea + (size_t)b.y * D + c0);
        acc.x += fmaxf(xv.x + av.x, 0.f);
        acc.y += fmaxf(xv.y + av.y, 0.f);
    }
    *(float2*)(h + (size_t)node * D + c0) = acc;
}

// ---------------- pack W1 (fp32 row-major) -> bf16 fragment image ----------
__global__ __launch_bounds__(256) void k_packW(
    const float* __restrict__ W, short* __restrict__ wp)
{
    int gid = blockIdx.x * 256 + threadIdx.x;   // 2048 threads
    int f = gid & 127;
    int kb = gid >> 7;                           // 16 k-blocks of 8
    #pragma unroll
    for (int e = 0; e < 8; ++e) {
        int k = kb * 8 + e;
        wp[wslot(k, f)] = f2bf(W[k * D + f]);
    }
}

// ---------------- MFMA GEMM: out = [relu](hin @ W + bias) ------------------
// Operand-swapped: D[f][r] = sum_k Wfrag[f][k] * rowfrag[k][r].
// C/D mapping (m89): col=lane&15 -> output ROW (cl), row=(lane>>4)*4+reg ->
// 4 CONSECUTIVE features -> float4 stores. No aliasing, no stats, no branches
// in the full-tile fast path.
template<int RELU>
__global__ __launch_bounds__(256) void k_mgemm(
    const float* __restrict__ hin, const short* __restrict__ wp,
    const float* __restrict__ bias, float* __restrict__ outp, int N)
{
    __shared__ __align__(16) short wB[D * D];   // 32KB packed frags
    int tid = threadIdx.x;
    #pragma unroll
    for (int i = 0; i < 8; ++i) {
        int q = i * 256 + tid;                   // 2048 x 16B = 32KB, linear
        *(s16x8*)&wB[q * 8] = *(const s16x8*)&wp[q * 8];
    }
    __syncthreads();

    int wv = tid >> 6, l = tid & 63;
    int cl = l & 15, kg = l >> 4;
    int ntiles = (N + 15) >> 4;

    float4 bv[8];
    #pragma unroll
    for (int c = 0; c < 8; ++c) bv[c] = *(const float4*)&bias[c * 16 + kg * 4];

    for (int tile = blockIdx.x * 4 + wv; tile < ntiles; tile += gridDim.x * 4) {
        int row0 = tile * 16;
        int rowA = min(row0 + cl, N - 1);
        const float* ap = hin + (size_t)rowA * D + kg * 8;
        s16x8 rF[4];
        #pragma unroll
        for (int t = 0; t < 4; ++t) {
            float4 lo = *(const float4*)(ap + t * 32);
            float4 hi = *(const float4*)(ap + t * 32 + 4);
            s16x8 a;
            a[0] = f2bf(lo.x); a[1] = f2bf(lo.y); a[2] = f2bf(lo.z); a[3] = f2bf(lo.w);
            a[4] = f2bf(hi.x); a[5] = f2bf(hi.y); a[6] = f2bf(hi.z); a[7] = f2bf(hi.w);
            rF[t] = a;
        }
        bool ok = (row0 + cl < N);
        float* op = outp + (size_t)(row0 + cl) * D + kg * 4;
        #pragma unroll
        for (int c = 0; c < 8; ++c) {
            f32x4 acc = { bv[c].x, bv[c].y, bv[c].z, bv[c].w };
            #pragma unroll
            for (int t = 0; t < 4; ++t) {
                s16x8 wF = *(const s16x8*)&wB[((t * 8 + c) * 64 + l) * 8];
                acc = __builtin_amdgcn_mfma_f32_16x16x32_bf16(wF, rF[t], acc, 0, 0, 0);
            }
            if (RELU) {
                acc[0] = fmaxf(acc[0], 0.f); acc[1] = fmaxf(acc[1], 0.f);
                acc[2] = fmaxf(acc[2], 0.f); acc[3] = fmaxf(acc[3], 0.f);
            }
            if (ok)
                *(float4*)(op + c * 16) = make_float4(acc[0], acc[1], acc[2], acc[3]);
        }
    }
}

// ---------------- BN batch stats over h1: gsum/gsq per feature -------------
__global__ __launch_bounds__(256) void k_stats(
    const float* __restrict__ h1, float* __restrict__ gsum,
    float* __restrict__ gsq, int N)
{
    __shared__ float ls[D], lq[D];
    int tid = threadIdx.x;
    if (tid < D) { ls[tid] = 0.f; lq[tid] = 0.f; }
    __syncthreads();
    int cq = tid & 31, c0 = cq * 4;
    float4 s = make_float4(0.f, 0.f, 0.f, 0.f);
    float4 q = make_float4(0.f, 0.f, 0.f, 0.f);
    for (int r = blockIdx.x * 8 + (tid >> 5); r < N; r += gridDim.x * 8) {
        float4 v = *(const float4*)&h1[(size_t)r * D + c0];
        s.x += v.x; s.y += v.y; s.z += v.z; s.w += v.w;
        q.x += v.x * v.x; q.y += v.y * v.y; q.z += v.z * v.z; q.w += v.w * v.w;
    }
    atomicAdd(&ls[c0 + 0], s.x); atomicAdd(&ls[c0 + 1], s.y);
    atomicAdd(&ls[c0 + 2], s.z); atomicAdd(&ls[c0 + 3], s.w);
    atomicAdd(&lq[c0 + 0], q.x); atomicAdd(&lq[c0 + 1], q.y);
    atomicAdd(&lq[c0 + 2], q.z); atomicAdd(&lq[c0 + 3], q.w);
    __syncthreads();
    if (tid < D) {
        atomicAdd(&gsum[tid], ls[tid]);
        atomicAdd(&gsq[tid], lq[tid]);
    }
}

// ---------------- fold BN into W2/b2; emit PACKED bf16 W2' + b2' -----------
__global__ __launch_bounds__(128) void k_fold(
    const float* __restrict__ gsum, const float* __restrict__ gsq,
    const float* __restrict__ gamma, const float* __restrict__ beta,
    const float* __restrict__ W2, const float* __restrict__ b2,
    short* __restrict__ wp2, float* __restrict__ b2p, int N)
{
    __shared__ float sS[D], tS[D];
    int j = threadIdx.x;
    float invN = 1.0f / (float)N;
    float mean = gsum[j] * invN;
    float var = gsq[j] * invN - mean * mean;
    float rstd = rsqrtf(var + BN_EPS);
    float s = rstd * gamma[j];
    sS[j] = s;
    tS[j] = beta[j] - mean * s;
    __syncthreads();
    float acc = b2[j];
    #pragma unroll 4
    for (int k = 0; k < D; ++k) {
        float w = W2[k * D + j];
        wp2[wslot(k, j)] = f2bf(sS[k] * w);
        acc = fmaf(tS[k], w, acc);
    }
    b2p[j] = acc;
}

extern "C" void kernel_launch(void* const* d_in, const int* in_sizes, int n_in,
                              void* d_out, int out_size, void* d_ws, size_t ws_size,
                              hipStream_t stream) {
    const float* x     = (const float*)d_in[0];
    const int*   ei    = (const int*)d_in[1];
    const float* ea    = (const float*)d_in[2];
    const float* W1    = (const float*)d_in[3];
    const float* b1    = (const float*)d_in[4];
    const float* gamma = (const float*)d_in[5];
    const float* beta  = (const float*)d_in[6];
    const float* W2    = (const float*)d_in[7];
    const float* b2    = (const float*)d_in[8];
    float* out = (float*)d_out;

    int N = in_sizes[0] / D;
    int E = in_sizes[1] / 2;

    // ---- workspace layout (proven prefix kept; ~117 MB of ~3.3 GB) ----
    char* ws = (char*)d_ws;
    int2*  bucket = (int2*)ws;                             // E int2 (12.8 MB)
    int*   deg    = (int*)(ws + (size_t)E * sizeof(int2)); // N
    int*   offs   = deg + N;                               // N
    int*   cur    = offs + N;                              // N
    int*   bsum   = cur + N;                               // SB
    float* gsum   = (float*)(bsum + SB);                   // D
    float* gsq    = gsum + D;                              // D
    float* b2p    = gsq + D;                               // D
    short* wp1    = (short*)(b2p + D);                     // D*D bf16 (32 KB)
    short* wp2    = wp1 + D * D;                           // D*D bf16 (32 KB)
    float* h      = (float*)(wp2 + D * D);                 // N*D fp32 (51.2 MB)
    float* h1     = h + (size_t)N * D;                     // N*D fp32 (51.2 MB)

    // zero deg + bsum + gsum + gsq (rest fully overwritten)
    hipMemsetAsync(deg, 0, ((size_t)3 * N + SB) * sizeof(int) + 2 * D * sizeof(float), stream);

    int chunk = (N + SB - 1) / SB;
    int eB = (E + 255) / 256;

    k_hist<<<eB, 256, 0, stream>>>(ei, deg, E);
    k_scanA<<<SB, ST, 0, stream>>>(deg, bsum, N, chunk);
    k_scanB<<<1, SB, 0, stream>>>(bsum);
    k_scanC<<<SB, ST, 0, stream>>>(deg, bsum, offs, cur, N, chunk);
    k_scatter<<<eB, 256, 0, stream>>>(ei, cur, bucket, E);
    k_aggr<<<(N + 3) / 4, 256, 0, stream>>>(x, ea, bucket, offs, deg, h, N);

    k_packW<<<8, 256, 0, stream>>>(W1, wp1);
    k_mgemm<1><<<1024, 256, 0, stream>>>(h, wp1, b1, h1, N);
    k_stats<<<512, 256, 0, stream>>>(h1, gsum, gsq, N);
    k_fold<<<1, 128, 0, stream>>>(gsum, gsq, gamma, beta, W2, b2, wp2, b2p, N);
    k_mgemm<0><<<1024, 256, 0, stream>>>(h1, wp2, b2p, out, N);
}

// Round 8
// 529.932 us; speedup vs baseline: 2.1695x; 1.0099x over previous
//
#include <hip/hip_runtime.h>

#define D 128
#define BN_EPS 1e-5f
#define SB 256   // scan blocks
#define ST 256   // scan threads

typedef short s16x8 __attribute__((ext_vector_type(8)));
typedef float f32x4 __attribute__((ext_vector_type(4)));
typedef int   i32x2 __attribute__((ext_vector_type(2)));

// fp32 -> bf16 round-to-nearest-even
static __device__ __forceinline__ short f2bf(float f) {
    unsigned u = __builtin_bit_cast(unsigned, f);
    u += 0x7FFFu + ((u >> 16) & 1u);
    return (short)(u >> 16);
}

// packed-fragment slot for W element (k, f)
static __device__ __forceinline__ int wslot(int k, int f) {
    int t = k >> 5, kg = (k >> 3) & 3, e = k & 7;
    int c = f >> 4, fl = f & 15;
    return (((t * 8 + c) * 64 + kg * 16 + fl) * 8) + e;
}

// ---------------- 1. histogram: deg[dst]++ --------------------------------
__global__ __launch_bounds__(256) void k_hist(
    const int* __restrict__ ei, int* __restrict__ deg, int E)
{
    int e = blockIdx.x * 256 + threadIdx.x;
    if (e >= E) return;
    atomicAdd(&deg[ei[E + e]], 1);
}

// ---------------- 2a. per-block partial sums -------------------------------
__global__ __launch_bounds__(ST) void k_scanA(
    const int* __restrict__ deg, int* __restrict__ bsum, int N, int chunk)
{
    int b = blockIdx.x;
    int start = b * chunk, end = min(start + chunk, N);
    int s = 0;
    for (int i = start + threadIdx.x; i < end; i += ST) s += deg[i];
    __shared__ int red[ST];
    red[threadIdx.x] = s;
    __syncthreads();
    for (int o = ST / 2; o > 0; o >>= 1) {
        if (threadIdx.x < o) red[threadIdx.x] += red[threadIdx.x + o];
        __syncthreads();
    }
    if (threadIdx.x == 0) bsum[b] = red[0];
}

// ---------------- 2b. exclusive scan of block sums (1 block) ---------------
__global__ __launch_bounds__(SB) void k_scanB(int* __restrict__ bsum)
{
    __shared__ int tmp[SB];
    int t = threadIdx.x;
    int orig = bsum[t];
    tmp[t] = orig;
    __syncthreads();
    for (int o = 1; o < SB; o <<= 1) {
        int u = (t >= o) ? tmp[t - o] : 0;
        __syncthreads();
        tmp[t] += u;
        __syncthreads();
    }
    bsum[t] = tmp[t] - orig;   // exclusive
}

// ---------------- 2c. per-block scan with base → offsets + cursor ----------
__global__ __launch_bounds__(ST) void k_scanC(
    const int* __restrict__ deg, const int* __restrict__ bsum,
    int* __restrict__ offs, int* __restrict__ cur, int N, int chunk)
{
    int b = blockIdx.x;
    int start = b * chunk, end = min(start + chunk, N);
    __shared__ int tmp[ST];
    __shared__ int carry;
    int t = threadIdx.x;
    if (t == 0) carry = bsum[b];
    __syncthreads();
    for (int i0 = start; i0 < end; i0 += ST) {
        int i = i0 + t;
        int v = (i < end) ? deg[i] : 0;
        tmp[t] = v;
        __syncthreads();
        for (int o = 1; o < ST; o <<= 1) {
            int u = (t >= o) ? tmp[t - o] : 0;
            __syncthreads();
            tmp[t] += u;
            __syncthreads();
        }
        int incl = tmp[t];
        int total = tmp[ST - 1];
        if (i < end) {
            int ex = carry + incl - v;
            offs[i] = ex;
            cur[i] = ex;
        }
        __syncthreads();
        if (t == 0) carry += total;
        __syncthreads();
    }
}

// ---------------- 3. scatter (src, eid) into dst buckets -------------------
__global__ __launch_bounds__(256) void k_scatter(
    const int* __restrict__ ei, int* __restrict__ cur,
    int2* __restrict__ bucket, int E)
{
    int e = blockIdx.x * 256 + threadIdx.x;
    if (e >= E) return;
    int dst = ei[E + e];
    int pos = atomicAdd(&cur[dst], 1);
    bucket[pos] = make_int2(ei[e], e);
}

// ---------------- 4. aggregate: h[n] = x[n] + sum relu(x[src]+ea[eid]) -----
// 2 nodes per 64-lane wave (32 lanes x float4 each); ea/bucket loads are
// NONTEMPORAL (single-use streams must not evict x from L3); unroll x4.
__global__ __launch_bounds__(256) void k_aggr(
    const float* __restrict__ x, const float* __restrict__ ea,
    const int2* __restrict__ bucket, const int* __restrict__ offs,
    const int* __restrict__ deg, float* __restrict__ h, int N)
{
    int node = blockIdx.x * 8 + (threadIdx.x >> 5);
    if (node >= N) return;
    int lane = threadIdx.x & 31;
    int c0 = lane * 4;
    int start = offs[node];
    int d = deg[node];
    const int2* bp = bucket + start;

    f32x4 acc = *(const f32x4*)(x + (size_t)node * D + c0);  // (1+eps)*x_i, eps=0

    int e = 0;
    for (; e + 4 <= d; e += 4) {
        i32x2 b[4];
        #pragma unroll
        for (int j = 0; j < 4; ++j)
            b[j] = __builtin_nontemporal_load((const i32x2*)(bp + e + j));
        f32x4 xv[4], av[4];
        #pragma unroll
        for (int j = 0; j < 4; ++j) {
            xv[j] = *(const f32x4*)(x + (size_t)b[j][0] * D + c0);
            av[j] = __builtin_nontemporal_load((const f32x4*)(ea + (size_t)b[j][1] * D + c0));
        }
        #pragma unroll
        for (int j = 0; j < 4; ++j) {
            acc[0] += fmaxf(xv[j][0] + av[j][0], 0.f);
            acc[1] += fmaxf(xv[j][1] + av[j][1], 0.f);
            acc[2] += fmaxf(xv[j][2] + av[j][2], 0.f);
            acc[3] += fmaxf(xv[j][3] + av[j][3], 0.f);
        }
    }
    for (; e < d; ++e) {
        i32x2 b = __builtin_nontemporal_load((const i32x2*)(bp + e));
        f32x4 xv = *(const f32x4*)(x + (size_t)b[0] * D + c0);
        f32x4 av = __builtin_nontemporal_load((const f32x4*)(ea + (size_t)b[1] * D + c0));
        acc[0] += fmaxf(xv[0] + av[0], 0.f);
        acc[1] += fmaxf(xv[1] + av[1], 0.f);
        acc[2] += fmaxf(xv[2] + av[2], 0.f);
        acc[3] += fmaxf(xv[3] + av[3], 0.f);
    }
    *(f32x4*)(h + (size_t)node * D + c0) = acc;
}

// ---------------- pack W1 (fp32 row-major) -> bf16 fragment image ----------
__global__ __launch_bounds__(256) void k_packW(
    const float* __restrict__ W, short* __restrict__ wp)
{
    int gid = blockIdx.x * 256 + threadIdx.x;   // 2048 threads
    int f = gid & 127;
    int kb = gid >> 7;                           // 16 k-blocks of 8
    #pragma unroll
    for (int e = 0; e < 8; ++e) {
        int k = kb * 8 + e;
        wp[wslot(k, f)] = f2bf(W[k * D + f]);
    }
}

// ---------------- MFMA GEMM: out = [relu](hin @ W + bias) ------------------
// Operand-swapped (proven round 7): D[f][r]; float4 epilogue stores.
template<int RELU>
__global__ __launch_bounds__(256) void k_mgemm(
    const float* __restrict__ hin, const short* __restrict__ wp,
    const float* __restrict__ bias, float* __restrict__ outp, int N)
{
    __shared__ __align__(16) short wB[D * D];   // 32KB packed frags
    int tid = threadIdx.x;
    #pragma unroll
    for (int i = 0; i < 8; ++i) {
        int q = i * 256 + tid;                   // 2048 x 16B = 32KB, linear
        *(s16x8*)&wB[q * 8] = *(const s16x8*)&wp[q * 8];
    }
    __syncthreads();

    int wv = tid >> 6, l = tid & 63;
    int cl = l & 15, kg = l >> 4;
    int ntiles = (N + 15) >> 4;

    float4 bv[8];
    #pragma unroll
    for (int c = 0; c < 8; ++c) bv[c] = *(const float4*)&bias[c * 16 + kg * 4];

    for (int tile = blockIdx.x * 4 + wv; tile < ntiles; tile += gridDim.x * 4) {
        int row0 = tile * 16;
        int rowA = min(row0 + cl, N - 1);
        const float* ap = hin + (size_t)rowA * D + kg * 8;
        s16x8 rF[4];
        #pragma unroll
        for (int t = 0; t < 4; ++t) {
            float4 lo = *(const float4*)(ap + t * 32);
            float4 hi = *(const float4*)(ap + t * 32 + 4);
            s16x8 a;
            a[0] = f2bf(lo.x); a[1] = f2bf(lo.y); a[2] = f2bf(lo.z); a[3] = f2bf(lo.w);
            a[4] = f2bf(hi.x); a[5] = f2bf(hi.y); a[6] = f2bf(hi.z); a[7] = f2bf(hi.w);
            rF[t] = a;
        }
        bool ok = (row0 + cl < N);
        float* op = outp + (size_t)(row0 + cl) * D + kg * 4;
        #pragma unroll
        for (int c = 0; c < 8; ++c) {
            f32x4 acc = { bv[c].x, bv[c].y, bv[c].z, bv[c].w };
            #pragma unroll
            for (int t = 0; t < 4; ++t) {
                s16x8 wF = *(const s16x8*)&wB[((t * 8 + c) * 64 + l) * 8];
                acc = __builtin_amdgcn_mfma_f32_16x16x32_bf16(wF, rF[t], acc, 0, 0, 0);
            }
            if (RELU) {
                acc[0] = fmaxf(acc[0], 0.f); acc[1] = fmaxf(acc[1], 0.f);
                acc[2] = fmaxf(acc[2], 0.f); acc[3] = fmaxf(acc[3], 0.f);
            }
            if (ok)
                *(float4*)(op + c * 16) = make_float4(acc[0], acc[1], acc[2], acc[3]);
        }
    }
}

// ---------------- BN batch stats over h1: gsum/gsq per feature -------------
__global__ __launch_bounds__(256) void k_stats(
    const float* __restrict__ h1, float* __restrict__ gsum,
    float* __restrict__ gsq, int N)
{
    __shared__ float ls[D], lq[D];
    int tid = threadIdx.x;
    if (tid < D) { ls[tid] = 0.f; lq[tid] = 0.f; }
    __syncthreads();
    int cq = tid & 31, c0 = cq * 4;
    float4 s = make_float4(0.f, 0.f, 0.f, 0.f);
    float4 q = make_float4(0.f, 0.f, 0.f, 0.f);
    for (int r = blockIdx.x * 8 + (tid >> 5); r < N; r += gridDim.x * 8) {
        float4 v = *(const float4*)&h1[(size_t)r * D + c0];
        s.x += v.x; s.y += v.y; s.z += v.z; s.w += v.w;
        q.x += v.x * v.x; q.y += v.y * v.y; q.z += v.z * v.z; q.w += v.w * v.w;
    }
    atomicAdd(&ls[c0 + 0], s.x); atomicAdd(&ls[c0 + 1], s.y);
    atomicAdd(&ls[c0 + 2], s.z); atomicAdd(&ls[c0 + 3], s.w);
    atomicAdd(&lq[c0 + 0], q.x); atomicAdd(&lq[c0 + 1], q.y);
    atomicAdd(&lq[c0 + 2], q.z); atomicAdd(&lq[c0 + 3], q.w);
    __syncthreads();
    if (tid < D) {
        atomicAdd(&gsum[tid], ls[tid]);
        atomicAdd(&gsq[tid], lq[tid]);
    }
}

// ---------------- fold BN into W2/b2; emit PACKED bf16 W2' + b2' -----------
__global__ __launch_bounds__(128) void k_fold(
    const float* __restrict__ gsum, const float* __restrict__ gsq,
    const float* __restrict__ gamma, const float* __restrict__ beta,
    const float* __restrict__ W2, const float* __restrict__ b2,
    short* __restrict__ wp2, float* __restrict__ b2p, int N)
{
    __shared__ float sS[D], tS[D];
    int j = threadIdx.x;
    float invN = 1.0f / (float)N;
    float mean = gsum[j] * invN;
    float var = gsq[j] * invN - mean * mean;
    float rstd = rsqrtf(var + BN_EPS);
    float s = rstd * gamma[j];
    sS[j] = s;
    tS[j] = beta[j] - mean * s;
    __syncthreads();
    float acc = b2[j];
    #pragma unroll 4
    for (int k = 0; k < D; ++k) {
        float w = W2[k * D + j];
        wp2[wslot(k, j)] = f2bf(sS[k] * w);
        acc = fmaf(tS[k], w, acc);
    }
    b2p[j] = acc;
}

extern "C" void kernel_launch(void* const* d_in, const int* in_sizes, int n_in,
                              void* d_out, int out_size, void* d_ws, size_t ws_size,
                              hipStream_t stream) {
    const float* x     = (const float*)d_in[0];
    const int*   ei    = (const int*)d_in[1];
    const float* ea    = (const float*)d_in[2];
    const float* W1    = (const float*)d_in[3];
    const float* b1    = (const float*)d_in[4];
    const float* gamma = (const float*)d_in[5];
    const float* beta  = (const float*)d_in[6];
    const float* W2    = (const float*)d_in[7];
    const float* b2    = (const float*)d_in[8];
    float* out = (float*)d_out;

    int N = in_sizes[0] / D;
    int E = in_sizes[1] / 2;

    // ---- workspace layout (proven round 7) ----
    char* ws = (char*)d_ws;
    int2*  bucket = (int2*)ws;                             // E int2 (12.8 MB)
    int*   deg    = (int*)(ws + (size_t)E * sizeof(int2)); // N
    int*   offs   = deg + N;                               // N
    int*   cur    = offs + N;                              // N
    int*   bsum   = cur + N;                               // SB
    float* gsum   = (float*)(bsum + SB);                   // D
    float* gsq    = gsum + D;                              // D
    float* b2p    = gsq + D;                               // D
    short* wp1    = (short*)(b2p + D);                     // D*D bf16 (32 KB)
    short* wp2    = wp1 + D * D;                           // D*D bf16 (32 KB)
    float* h      = (float*)(wp2 + D * D);                 // N*D fp32 (51.2 MB)
    float* h1     = h + (size_t)N * D;                     // N*D fp32 (51.2 MB)

    // zero deg + bsum + gsum + gsq (rest fully overwritten)
    hipMemsetAsync(deg, 0, ((size_t)3 * N + SB) * sizeof(int) + 2 * D * sizeof(float), stream);

    int chunk = (N + SB - 1) / SB;
    int eB = (E + 255) / 256;

    k_hist<<<eB, 256, 0, stream>>>(ei, deg, E);
    k_scanA<<<SB, ST, 0, stream>>>(deg, bsum, N, chunk);
    k_scanB<<<1, SB, 0, stream>>>(bsum);
    k_scanC<<<SB, ST, 0, stream>>>(deg, bsum, offs, cur, N, chunk);
    k_scatter<<<eB, 256, 0, stream>>>(ei, cur, bucket, E);
    k_aggr<<<(N + 7) / 8, 256, 0, stream>>>(x, ea, bucket, offs, deg, h, N);

    int ntiles = (N + 15) / 16;
    int gB = (ntiles + 7) / 8;   // each wave: exactly 2 tiles
    k_packW<<<8, 256, 0, stream>>>(W1, wp1);
    k_mgemm<1><<<gB, 256, 0, stream>>>(h, wp1, b1, h1, N);
    k_stats<<<512, 256, 0, stream>>>(h1, gsum, gsq, N);
    k_fold<<<1, 128, 0, stream>>>(gsum, gsq, gamma, beta, W2, b2, wp2, b2p, N);
    k_mgemm<0><<<gB, 256, 0, stream>>>(h1, wp2, b2p, out, N);
}

// Round 10
// 526.907 us; speedup vs baseline: 2.1819x; 1.0057x over previous
//
#include <hip/hip_runtime.h>

#define D 128
#define BN_EPS 1e-5f
#define SB 256   // scan blocks
#define ST 256   // scan threads

typedef short s16x8 __attribute__((ext_vector_type(8)));
typedef short s16x4 __attribute__((ext_vector_type(4)));
typedef float f32x4 __attribute__((ext_vector_type(4)));
typedef int   i32x2 __attribute__((ext_vector_type(2)));

// fp32 -> bf16 round-to-nearest-even
static __device__ __forceinline__ short f2bf(float f) {
    unsigned u = __builtin_bit_cast(unsigned, f);
    u += 0x7FFFu + ((u >> 16) & 1u);
    return (short)(u >> 16);
}
static __device__ __forceinline__ float bf2f(short s) {
    unsigned u = ((unsigned)(unsigned short)s) << 16;
    return __builtin_bit_cast(float, u);
}

// packed-fragment slot for W element (k, f)
static __device__ __forceinline__ int wslot(int k, int f) {
    int t = k >> 5, kg = (k >> 3) & 3, e = k & 7;
    int c = f >> 4, fl = f & 15;
    return (((t * 8 + c) * 64 + kg * 16 + fl) * 8) + e;
}

// ---------------- 0. cast x -> bf16 image (gather working set 25.6 MB) -----
__global__ __launch_bounds__(256) void k_xcast(
    const float* __restrict__ x, short* __restrict__ xb, int total8)
{
    int i = blockIdx.x * 256 + threadIdx.x;
    if (i >= total8) return;
    const float* p = x + (size_t)i * 8;
    f32x4 lo = __builtin_nontemporal_load((const f32x4*)p);
    f32x4 hi = __builtin_nontemporal_load((const f32x4*)(p + 4));
    s16x8 o;
    o[0] = f2bf(lo[0]); o[1] = f2bf(lo[1]); o[2] = f2bf(lo[2]); o[3] = f2bf(lo[3]);
    o[4] = f2bf(hi[0]); o[5] = f2bf(hi[1]); o[6] = f2bf(hi[2]); o[7] = f2bf(hi[3]);
    *(s16x8*)(xb + (size_t)i * 8) = o;
}

// ---------------- 1. histogram: deg[dst]++ --------------------------------
__global__ __launch_bounds__(256) void k_hist(
    const int* __restrict__ ei, int* __restrict__ deg, int E)
{
    int e = blockIdx.x * 256 + threadIdx.x;
    if (e >= E) return;
    atomicAdd(&deg[ei[E + e]], 1);
}

// ---------------- 2a. per-block partial sums -------------------------------
__global__ __launch_bounds__(ST) void k_scanA(
    const int* __restrict__ deg, int* __restrict__ bsum, int N, int chunk)
{
    int b = blockIdx.x;
    int start = b * chunk, end = min(start + chunk, N);
    int s = 0;
    for (int i = start + threadIdx.x; i < end; i += ST) s += deg[i];
    __shared__ int red[ST];
    red[threadIdx.x] = s;
    __syncthreads();
    for (int o = ST / 2; o > 0; o >>= 1) {
        if (threadIdx.x < o) red[threadIdx.x] += red[threadIdx.x + o];
        __syncthreads();
    }
    if (threadIdx.x == 0) bsum[b] = red[0];
}

// ---------------- 2b. exclusive scan of block sums (1 block) ---------------
__global__ __launch_bounds__(SB) void k_scanB(int* __restrict__ bsum)
{
    __shared__ int tmp[SB];
    int t = threadIdx.x;
    int orig = bsum[t];
    tmp[t] = orig;
    __syncthreads();
    for (int o = 1; o < SB; o <<= 1) {
        int u = (t >= o) ? tmp[t - o] : 0;
        __syncthreads();
        tmp[t] += u;
        __syncthreads();
    }
    bsum[t] = tmp[t] - orig;   // exclusive
}

// ---------------- 2c. per-block scan with base → offsets + cursor ----------
__global__ __launch_bounds__(ST) void k_scanC(
    const int* __restrict__ deg, const int* __restrict__ bsum,
    int* __restrict__ offs, int* __restrict__ cur, int N, int chunk)
{
    int b = blockIdx.x;
    int start = b * chunk, end = min(start + chunk, N);
    __shared__ int tmp[ST];
    __shared__ int carry;
    int t = threadIdx.x;
    if (t == 0) carry = bsum[b];
    __syncthreads();
    for (int i0 = start; i0 < end; i0 += ST) {
        int i = i0 + t;
        int v = (i < end) ? deg[i] : 0;
        tmp[t] = v;
        __syncthreads();
        for (int o = 1; o < ST; o <<= 1) {
            int u = (t >= o) ? tmp[t - o] : 0;
            __syncthreads();
            tmp[t] += u;
            __syncthreads();
        }
        int incl = tmp[t];
        int total = tmp[ST - 1];
        if (i < end) {
            int ex = carry + incl - v;
            offs[i] = ex;
            cur[i] = ex;
        }
        __syncthreads();
        if (t == 0) carry += total;
        __syncthreads();
    }
}

// ---------------- 3. scatter (src, eid) into dst buckets -------------------
__global__ __launch_bounds__(256) void k_scatter(
    const int* __restrict__ ei, int* __restrict__ cur,
    int2* __restrict__ bucket, int E)
{
    int e = blockIdx.x * 256 + threadIdx.x;
    if (e >= E) return;
    int dst = ei[E + e];
    int pos = atomicAdd(&cur[dst], 1);
    bucket[pos] = make_int2(ei[e], e);
}

// ---------------- 4. aggregate: h[n] = bf16(x[n] + sum relu(x[src]+ea)) ----
// 4 nodes per 64-lane wave (16 lanes x 8 features each); x gathered as bf16
// (L3-resident 25.6MB); ea/bucket NT; unroll x4 -> 12 loads in flight/lane.
__global__ __launch_bounds__(256) void k_aggr(
    const short* __restrict__ xb, const float* __restrict__ ea,
    const int2* __restrict__ bucket, const int* __restrict__ offs,
    const int* __restrict__ deg, short* __restrict__ h, int N)
{
    int node = blockIdx.x * 16 + (threadIdx.x >> 4);
    if (node >= N) return;
    int lane = threadIdx.x & 15;
    int c0 = lane * 8;
    int start = offs[node];
    int d = deg[node];
    const int2* bp = bucket + start;

    float acc[8];
    {
        s16x8 xs = *(const s16x8*)(xb + (size_t)node * D + c0);
        #pragma unroll
        for (int i = 0; i < 8; ++i) acc[i] = bf2f(xs[i]);
    }

    int e = 0;
    for (; e + 4 <= d; e += 4) {
        i32x2 b[4];
        #pragma unroll
        for (int j = 0; j < 4; ++j)
            b[j] = __builtin_nontemporal_load((const i32x2*)(bp + e + j));
        s16x8 xv[4];
        f32x4 a0[4], a1[4];
        #pragma unroll
        for (int j = 0; j < 4; ++j) {
            xv[j] = *(const s16x8*)(xb + (size_t)b[j][0] * D + c0);
            const float* ap = ea + (size_t)b[j][1] * D + c0;
            a0[j] = __builtin_nontemporal_load((const f32x4*)ap);
            a1[j] = __builtin_nontemporal_load((const f32x4*)(ap + 4));
        }
        #pragma unroll
        for (int j = 0; j < 4; ++j) {
            #pragma unroll
            for (int i = 0; i < 4; ++i) {
                acc[i]     += fmaxf(bf2f(xv[j][i])     + a0[j][i], 0.f);
                acc[i + 4] += fmaxf(bf2f(xv[j][i + 4]) + a1[j][i], 0.f);
            }
        }
    }
    for (; e < d; ++e) {
        i32x2 b = __builtin_nontemporal_load((const i32x2*)(bp + e));
        s16x8 xv = *(const s16x8*)(xb + (size_t)b[0] * D + c0);
        const float* ap = ea + (size_t)b[1] * D + c0;
        f32x4 a0 = __builtin_nontemporal_load((const f32x4*)ap);
        f32x4 a1 = __builtin_nontemporal_load((const f32x4*)(ap + 4));
        #pragma unroll
        for (int i = 0; i < 4; ++i) {
            acc[i]     += fmaxf(bf2f(xv[i])     + a0[i], 0.f);
            acc[i + 4] += fmaxf(bf2f(xv[i + 4]) + a1[i], 0.f);
        }
    }
    s16x8 o;
    #pragma unroll
    for (int i = 0; i < 8; ++i) o[i] = f2bf(acc[i]);
    *(s16x8*)(h + (size_t)node * D + c0) = o;
}

// ---------------- pack W1 (fp32 row-major) -> bf16 fragment image ----------
__global__ __launch_bounds__(256) void k_packW(
    const float* __restrict__ W, short* __restrict__ wp)
{
    int gid = blockIdx.x * 256 + threadIdx.x;   // 2048 threads
    int f = gid & 127;
    int kb = gid >> 7;
    #pragma unroll
    for (int e = 0; e < 8; ++e) {
        int k = kb * 8 + e;
        wp[wslot(k, f)] = f2bf(W[k * D + f]);
    }
}

// ---------------- MFMA GEMM: out = [relu](hin_bf16 @ W + bias) -------------
// Operand-swapped (proven r7): D[f][r]; B-frag rows load DIRECTLY as s16x8.
// OBF=1: bf16 output (8B stores); OBF=0: fp32 output (16B stores).
template<int RELU, int OBF>
__global__ __launch_bounds__(256) void k_mgemm(
    const short* __restrict__ hin, const short* __restrict__ wp,
    const float* __restrict__ bias, void* __restrict__ outp, int N)
{
    __shared__ __align__(16) short wB[D * D];   // 32KB packed frags
    int tid = threadIdx.x;
    #pragma unroll
    for (int i = 0; i < 8; ++i) {
        int q = i * 256 + tid;
        *(s16x8*)&wB[q * 8] = *(const s16x8*)&wp[q * 8];
    }
    __syncthreads();

    int wv = tid >> 6, l = tid & 63;
    int cl = l & 15, kg = l >> 4;
    int ntiles = (N + 15) >> 4;

    float4 bv[8];
    #pragma unroll
    for (int c = 0; c < 8; ++c) bv[c] = *(const float4*)&bias[c * 16 + kg * 4];

    for (int tile = blockIdx.x * 4 + wv; tile < ntiles; tile += gridDim.x * 4) {
        int row0 = tile * 16;
        int rowA = min(row0 + cl, N - 1);
        const short* ap = hin + (size_t)rowA * D + kg * 8;
        s16x8 rF[4];
        #pragma unroll
        for (int t = 0; t < 4; ++t)
            rF[t] = *(const s16x8*)(ap + t * 32);

        bool ok = (row0 + cl < N);
        size_t obase = (size_t)(row0 + cl) * D + kg * 4;
        #pragma unroll
        for (int c = 0; c < 8; ++c) {
            f32x4 acc = { bv[c].x, bv[c].y, bv[c].z, bv[c].w };
            #pragma unroll
            for (int t = 0; t < 4; ++t) {
                s16x8 wF = *(const s16x8*)&wB[((t * 8 + c) * 64 + l) * 8];
                acc = __builtin_amdgcn_mfma_f32_16x16x32_bf16(wF, rF[t], acc, 0, 0, 0);
            }
            if (RELU) {
                acc[0] = fmaxf(acc[0], 0.f); acc[1] = fmaxf(acc[1], 0.f);
                acc[2] = fmaxf(acc[2], 0.f); acc[3] = fmaxf(acc[3], 0.f);
            }
            if (ok) {
                if (OBF) {
                    s16x4 o = { f2bf(acc[0]), f2bf(acc[1]), f2bf(acc[2]), f2bf(acc[3]) };
                    *(s16x4*)((short*)outp + obase + c * 16) = o;
                } else {
                    *(float4*)((float*)outp + obase + c * 16) =
                        make_float4(acc[0], acc[1], acc[2], acc[3]);
                }
            }
        }
    }
}

// ---------------- BN batch stats over bf16 h1 ------------------------------
__global__ __launch_bounds__(256) void k_stats(
    const short* __restrict__ h1, float* __restrict__ gsum,
    float* __restrict__ gsq, int N)
{
    __shared__ float ls[D], lq[D];
    int tid = threadIdx.x;
    if (tid < D) { ls[tid] = 0.f; lq[tid] = 0.f; }
    __syncthreads();
    int c0 = (tid & 15) * 8;
    float s[8], q[8];
    #pragma unroll
    for (int i = 0; i < 8; ++i) { s[i] = 0.f; q[i] = 0.f; }
    for (int r = blockIdx.x * 16 + (tid >> 4); r < N; r += gridDim.x * 16) {
        s16x8 v = *(const s16x8*)(h1 + (size_t)r * D + c0);
        #pragma unroll
        for (int i = 0; i < 8; ++i) {
            float f = bf2f(v[i]);
            s[i] += f; q[i] += f * f;
        }
    }
    #pragma unroll
    for (int i = 0; i < 8; ++i) {
        atomicAdd(&ls[c0 + i], s[i]);
        atomicAdd(&lq[c0 + i], q[i]);
    }
    __syncthreads();
    if (tid < D) {
        atomicAdd(&gsum[tid], ls[tid]);
        atomicAdd(&gsq[tid], lq[tid]);
    }
}

// ---------------- fold BN into W2/b2; emit PACKED bf16 W2' + b2' -----------
__global__ __launch_bounds__(128) void k_fold(
    const float* __restrict__ gsum, const float* __restrict__ gsq,
    const float* __restrict__ gamma, const float* __restrict__ beta,
    const float* __restrict__ W2, const float* __restrict__ b2,
    short* __restrict__ wp2, float* __restrict__ b2p, int N)
{
    __shared__ float sS[D], tS[D];
    int j = threadIdx.x;
    float invN = 1.0f / (float)N;
    float mean = gsum[j] * invN;
    float var = gsq[j] * invN - mean * mean;
    float rstd = rsqrtf(var + BN_EPS);
    float s = rstd * gamma[j];
    sS[j] = s;
    tS[j] = beta[j] - mean * s;
    __syncthreads();
    float acc = b2[j];
    #pragma unroll 4
    for (int k = 0; k < D; ++k) {
        float w = W2[k * D + j];
        wp2[wslot(k, j)] = f2bf(sS[k] * w);
        acc = fmaf(tS[k], w, acc);
    }
    b2p[j] = acc;
}

extern "C" void kernel_launch(void* const* d_in, const int* in_sizes, int n_in,
                              void* d_out, int out_size, void* d_ws, size_t ws_size,
                              hipStream_t stream) {
    const float* x     = (const float*)d_in[0];
    const int*   ei    = (const int*)d_in[1];
    const float* ea    = (const float*)d_in[2];
    const float* W1    = (const float*)d_in[3];
    const float* b1    = (const float*)d_in[4];
    const float* gamma = (const float*)d_in[5];
    const float* beta  = (const float*)d_in[6];
    const float* W2    = (const float*)d_in[7];
    const float* b2    = (const float*)d_in[8];
    float* out = (float*)d_out;

    int N = in_sizes[0] / D;
    int E = in_sizes[1] / 2;

    // ---- workspace layout (memset region contiguous: deg|gsum|gsq) ----
    char* ws = (char*)d_ws;
    int2*  bucket = (int2*)ws;                             // E int2 (12.8 MB)
    int*   deg    = (int*)(ws + (size_t)E * sizeof(int2)); // N
    float* gsum   = (float*)(deg + N);                     // D
    float* gsq    = gsum + D;                              // D
    float* b2p    = gsq + D;                               // D
    int*   offs   = (int*)(b2p + D);                       // N
    int*   cur    = offs + N;                              // N
    int*   bsum   = cur + N;                               // SB
    short* wp1    = (short*)(bsum + SB);                   // D*D bf16
    short* wp2    = wp1 + D * D;                           // D*D bf16
    short* xb     = wp2 + D * D;                           // N*D bf16 (25.6 MB)
    short* h      = xb + (size_t)N * D;                    // N*D bf16
    short* h1     = h + (size_t)N * D;                     // N*D bf16

    // zero deg + gsum + gsq (contiguous; rest fully overwritten)
    hipMemsetAsync(deg, 0, (size_t)N * sizeof(int) + 2 * D * sizeof(float), stream);

    int chunk = (N + SB - 1) / SB;
    int eB = (E + 255) / 256;
    int x8 = (N * D) / 8;

    k_xcast<<<(x8 + 255) / 256, 256, 0, stream>>>(x, xb, x8);
    k_hist<<<eB, 256, 0, stream>>>(ei, deg, E);
    k_scanA<<<SB, ST, 0, stream>>>(deg, bsum, N, chunk);
    k_scanB<<<1, SB, 0, stream>>>(bsum);
    k_scanC<<<SB, ST, 0, stream>>>(deg, bsum, offs, cur, N, chunk);
    k_scatter<<<eB, 256, 0, stream>>>(ei, cur, bucket, E);
    k_aggr<<<(N + 15) / 16, 256, 0, stream>>>(xb, ea, bucket, offs, deg, h, N);

    int ntiles = (N + 15) / 16;
    int gB = (ntiles + 7) / 8;   // each wave: exactly 2 tiles
    k_packW<<<8, 256, 0, stream>>>(W1, wp1);
    k_mgemm<1, 1><<<gB, 256, 0, stream>>>(h, wp1, b1, h1, N);
    k_stats<<<512, 256, 0, stream>>>(h1, gsum, gsq, N);
    k_fold<<<1, 128, 0, stream>>>(gsum, gsq, gamma, beta, W2, b2, wp2, b2p, N);
    k_mgemm<0, 0><<<gB, 256, 0, stream>>>(h1, wp2, b2p, out, N);
}